// Round 20
// baseline (121.801 us; speedup 1.0000x reference)
//
#include <hip/hip_runtime.h>
#include <hip/hip_bf16.h>

typedef unsigned int u32;
typedef unsigned short u16;
using bf16x8 = __attribute__((ext_vector_type(8))) short;
using f32x4  = __attribute__((ext_vector_type(4))) float;
using f32x16 = __attribute__((ext_vector_type(16))) float;

#define B_ 4
#define C_ 128
#define N_ 4096
#define D_ 128
#define NS1 16           // pass1 s-split (grid 512 = 2 blocks/CU at 512 thr)
#define NSEG (N_ / NS1)  // 256 n per pass1 slice
#define NCH (NSEG / 32)  // 8 chunks
#define NS2 6            // pass2 s-split (grid 768)
#define NCHUNK (N_ / 32) // 128 total 32-n chunks

// padded LDS strides (u16 units): 272B and 80B rows -> even bank spread
#define QS_STRIDE 136
#define VS_STRIDE 40
#define XS_STRIDE 68     // f32 units; 272B rows, 16B-aligned for float4 stores

__device__ __forceinline__ u16 f2bf(float f) {
    u32 x = __builtin_bit_cast(u32, f);
    x = x + 0x7fffu + ((x >> 16) & 1u);
    return (u16)(x >> 16);
}
__device__ __forceinline__ float bf2f(u16 h) {
    return __builtin_bit_cast(float, (u32)h << 16);
}
// pack two f32 -> one u32 of 2x bf16 (RNE), single VALU inst
__device__ __forceinline__ u32 cvtpk(float lo, float hi) {
    u32 d;
    asm("v_cvt_pk_bf16_f32 %0, %1, %2" : "=v"(d) : "v"(lo), "v"(hi));
    return d;
}
#define EXP2 __builtin_amdgcn_exp2f
__device__ __forceinline__ bf16x8 pack8(const float* v, float s) {
    bf16x8 r;
#pragma unroll
    for (int j = 0; j < 8; ++j) r[j] = (short)f2bf(v[j] * s);
    return r;
}

// ---------------- K1: projections ----------------
// Qbf[b][n][d] = sqrt(log2e) * sum_c Wqk[d][c] x[b][c][n]   (bf16)
// Vbf[b][d][n] = sum_c Wv[d][c] x[b][c][n] + bv[d]          (bf16)
__global__ __launch_bounds__(256) void k_proj(
        const float* __restrict__ x, const float* __restrict__ Wqk,
        const float* __restrict__ Wv, const float* __restrict__ bv,
        u16* __restrict__ Qbf, u16* __restrict__ Vbf) {
    __shared__ __align__(16) float xs[C_ * XS_STRIDE];
    const int bid = blockIdx.x;
    const int b  = bid >> 6;
    const int n0 = (bid & 63) << 6;
    const int t  = threadIdx.x;
    const float* xb = x + (size_t)b * C_ * N_;
#pragma unroll
    for (int i = 0; i < 8; ++i) {   // 128 rows x 16 float4 (vectorized staging)
        int idx = i * 256 + t;
        int c = idx >> 4, n4 = (idx & 15) * 4;
        *(float4*)&xs[c * XS_STRIDE + n4] = *(const float4*)&xb[(size_t)c * N_ + n0 + n4];
    }
    __syncthreads();
    const int lane = t & 63, w = t >> 6;
    const int l15 = lane & 15, g = lane >> 4;
    const float SC = 1.2011224087864498f;  // sqrt(log2(e))

    bf16x8 xf[4];  // A-frag rows n = n0+16w+l15, k = c
#pragma unroll
    for (int kk = 0; kk < 4; ++kk) {
        float tmp[8];
#pragma unroll
        for (int j = 0; j < 8; ++j) tmp[j] = xs[(kk * 32 + g * 8 + j) * XS_STRIDE + (16 * w + l15)];
        xf[kk] = pack8(tmp, 1.0f);
    }
    for (int dt = 0; dt < 8; ++dt) {
        const int d = dt * 16 + l15;
        bf16x8 wq[4], wv[4];
#pragma unroll
        for (int kk = 0; kk < 4; ++kk) {
            const float* pq = Wqk + (size_t)d * C_ + kk * 32 + g * 8;
            const float* pv = Wv  + (size_t)d * C_ + kk * 32 + g * 8;
            float a[8], c8[8];
#pragma unroll
            for (int j = 0; j < 8; ++j) { a[j] = pq[j]; c8[j] = pv[j]; }
            wq[kk] = pack8(a, SC);
            wv[kk] = pack8(c8, 1.0f);
        }
        f32x4 aq = {0.f, 0.f, 0.f, 0.f}, av = {0.f, 0.f, 0.f, 0.f};
        __builtin_amdgcn_s_setprio(1);
#pragma unroll
        for (int kk = 0; kk < 4; ++kk) {
            aq = __builtin_amdgcn_mfma_f32_16x16x32_bf16(xf[kk], wq[kk], aq, 0, 0, 0);
            av = __builtin_amdgcn_mfma_f32_16x16x32_bf16(wv[kk], xf[kk], av, 0, 0, 0);
        }
        __builtin_amdgcn_s_setprio(0);
#pragma unroll
        for (int r = 0; r < 4; ++r) {
            int nn = n0 + 16 * w + g * 4 + r;
            Qbf[((size_t)b * N_ + nn) * D_ + dt * 16 + l15] = f2bf(aq[r]);
            int dd = dt * 16 + g * 4 + r;
            Vbf[((size_t)b * D_ + dd) * N_ + n0 + 16 * w + l15] = f2bf(av[r] + bv[dd]);
        }
    }
}

// ---------------- K2: row sums of exp2(E'-64); 8 waves, 2 n-tiles per wave ----------------
// grid: bid = ((b*8 + ntile)*NS1) + s ; 8 waves, wave w owns n = ntile*512 + w*64 + [0,64)
__global__ __launch_bounds__(512, 4) void k_pass1(const u16* __restrict__ Qbf,
                                                  float* __restrict__ rsp) {
    __shared__ __align__(16) u16 qs[2][32 * QS_STRIDE];
    int bid = blockIdx.x;
    const int s = bid % NS1; bid /= NS1;
    const int ntile = bid & 7; const int b = bid >> 3;
    const int t = threadIdx.x, lane = t & 63, w = t >> 6;
    const int l31 = lane & 31, hi = lane >> 5;
    const int nb0 = ntile * 512 + w * 64;

    // B-frags for the two tiles: col n = nb0 + l31 and nb0 + 32 + l31
    bf16x8 bqn0[8], bqn1[8];
    {
        const u16* qn0 = Qbf + ((size_t)b * N_ + nb0 + l31) * D_ + hi * 8;
        const u16* qn1 = qn0 + (size_t)32 * D_;
#pragma unroll
        for (int dblk = 0; dblk < 8; ++dblk) {
            bqn0[dblk] = *(const bf16x8*)(qn0 + dblk * 16);
            bqn1[dblk] = *(const bf16x8*)(qn1 + dblk * 16);
        }
    }
    // staging map: 512 threads = 32 rows x 16 granules, one uint4 each (coalesced)
    const int srow = t >> 4, sslot = t & 15;
    const u16* qsrc = Qbf + ((size_t)b * N_ + s * NSEG + srow) * D_ + sslot * 8;
    const int qoff = srow * QS_STRIDE + sslot * 8;

    // prologue: stage chunk 0
    {
        uint4 a0 = *(const uint4*)qsrc;
        *(uint4*)&qs[0][qoff] = a0;
    }
    __syncthreads();

    float rs0 = 0.f, rs1 = 0.f, rs2 = 0.f, rs3 = 0.f;
    for (int mc = 0; mc < NCH; ++mc) {
        const int cur = mc & 1;
        uint4 qpre;
        if (mc < NCH - 1) qpre = *(const uint4*)(qsrc + (size_t)(mc + 1) * 32 * D_);
        // tile 0
        {
            f32x16 ea, eb;
#pragma unroll
            for (int i = 0; i < 16; ++i) { ea[i] = 0.f; eb[i] = 0.f; }
            __builtin_amdgcn_s_setprio(1);
#pragma unroll
            for (int dblk = 0; dblk < 4; ++dblk) {
                bf16x8 am0 = *(const bf16x8*)(qs[cur] + l31 * QS_STRIDE + (2 * dblk + hi) * 8);
                bf16x8 am1 = *(const bf16x8*)(qs[cur] + l31 * QS_STRIDE + (2 * (dblk + 4) + hi) * 8);
                ea = __builtin_amdgcn_mfma_f32_32x32x16_bf16(am0, bqn0[dblk], ea, 0, 0, 0);
                eb = __builtin_amdgcn_mfma_f32_32x32x16_bf16(am1, bqn0[dblk + 4], eb, 0, 0, 0);
            }
            __builtin_amdgcn_s_setprio(0);
#pragma unroll
            for (int r = 0; r < 16; r += 2) {
                rs0 += EXP2(ea[r] + eb[r] - 64.0f);
                rs1 += EXP2(ea[r + 1] + eb[r + 1] - 64.0f);
            }
        }
        // tile 1 (same staged A-tile, second B-frag set)
        {
            f32x16 ea, eb;
#pragma unroll
            for (int i = 0; i < 16; ++i) { ea[i] = 0.f; eb[i] = 0.f; }
            __builtin_amdgcn_s_setprio(1);
#pragma unroll
            for (int dblk = 0; dblk < 4; ++dblk) {
                bf16x8 am0 = *(const bf16x8*)(qs[cur] + l31 * QS_STRIDE + (2 * dblk + hi) * 8);
                bf16x8 am1 = *(const bf16x8*)(qs[cur] + l31 * QS_STRIDE + (2 * (dblk + 4) + hi) * 8);
                ea = __builtin_amdgcn_mfma_f32_32x32x16_bf16(am0, bqn1[dblk], ea, 0, 0, 0);
                eb = __builtin_amdgcn_mfma_f32_32x32x16_bf16(am1, bqn1[dblk + 4], eb, 0, 0, 0);
            }
            __builtin_amdgcn_s_setprio(0);
#pragma unroll
            for (int r = 0; r < 16; r += 2) {
                rs2 += EXP2(ea[r] + eb[r] - 64.0f);
                rs3 += EXP2(ea[r + 1] + eb[r + 1] - 64.0f);
            }
        }
        if (mc < NCH - 1) *(uint4*)&qs[cur ^ 1][qoff] = qpre;
        __syncthreads();
    }
    float rsA = rs0 + rs1, rsB = rs2 + rs3;
    rsA += __shfl_xor(rsA, 32);
    rsB += __shfl_xor(rsB, 32);
    if (lane < 32) {
        rsp[((size_t)s * B_ + b) * N_ + nb0 + l31] = rsA;
        rsp[((size_t)s * B_ + b) * N_ + nb0 + 32 + l31] = rsB;
    }
}

// ---------------- K3: irs = 1/sum_s(rsp) ----------------
__global__ void k_irs(const float* __restrict__ rsp, float* __restrict__ irs) {
    int i = blockIdx.x * 256 + threadIdx.x;
    if (i < B_ * N_) {
        float s = 0.f;
#pragma unroll
        for (int sp = 0; sp < NS1; ++sp) s += rsp[(size_t)sp * B_ * N_ + i];
        irs[i] = 1.0f / s;
    }
}

// ---------------- K4: R^T + cs partials; round-robin chunks ----------------
// grid: bid = (b*32 + mtile)*6 + s ; 4 waves, wave w owns m = mtile*128 + w*32 + [0,32)
// block s processes chunks c = s, s+6, s+12, ... (< 128)
__global__ __launch_bounds__(256, 3) void k_pass2(
        const u16* __restrict__ Qbf, const u16* __restrict__ Vbf,
        const float* __restrict__ irs, u32* __restrict__ Rp32,
        float* __restrict__ csp) {
    __shared__ __align__(16) u16 qs[2][32 * QS_STRIDE];
    __shared__ __align__(16) u16 vs[2][128 * VS_STRIDE];
    int bid = blockIdx.x;
    const int s = bid % NS2; bid /= NS2;
    const int mtile = bid & 31; const int b = bid >> 5;
    const int t = threadIdx.x, lane = t & 63, w = t >> 6;
    const int l31 = lane & 31, hi = lane >> 5;
    const int m0 = mtile * 128 + w * 32;

    // bq: E B-frags, col m = m0 + l31, k d  (once per block)
    bf16x8 bq[8];
    {
        const u16* qm = Qbf + ((size_t)b * N_ + m0 + l31) * D_ + hi * 8;
#pragma unroll
        for (int dblk = 0; dblk < 8; ++dblk) bq[dblk] = *(const bf16x8*)(qm + dblk * 16);
    }
    f32x16 acc[4];
#pragma unroll
    for (int i = 0; i < 4; ++i)
#pragma unroll
        for (int r = 0; r < 16; ++r) acc[i][r] = 0.f;
    float cs = 0.f;
    const float* irsb = irs + (size_t)b * N_;

    // staging maps (coalesced global -> padded LDS), 256 thr covers 2 rows each
    const int qrow = t >> 4, qslot = t & 15;          // Q: rows qrow, qrow+16
    const u16* qsrc = Qbf + ((size_t)b * N_ + qrow) * D_ + qslot * 8;
    const int qoff = qrow * QS_STRIDE + qslot * 8;
    const int vd = t >> 2, vslot = t & 3;             // V: rows vd, vd+64
    const u16* vsrc = Vbf + ((size_t)b * D_ + vd) * N_ + vslot * 8;
    const int voff = vd * VS_STRIDE + vslot * 8;

    // prologue: stage chunk c = s
    {
        const u16* q0 = qsrc + (size_t)s * 32 * D_;
        const u16* v0 = vsrc + s * 32;
        uint4 a0 = *(const uint4*)q0;
        uint4 a1 = *(const uint4*)(q0 + (size_t)16 * D_);
        uint4 b0 = *(const uint4*)v0;
        uint4 b1 = *(const uint4*)(v0 + (size_t)64 * N_);
        *(uint4*)&qs[0][qoff] = a0;
        *(uint4*)&qs[0][qoff + 16 * QS_STRIDE] = a1;
        *(uint4*)&vs[0][voff] = b0;
        *(uint4*)&vs[0][voff + 64 * VS_STRIDE] = b1;
    }
    __syncthreads();

    int iter = 0;
    for (int c = s; c < NCHUNK; c += NS2, ++iter) {
        const int cur = iter & 1;
        const int nb = c * 32;
        const int cn = c + NS2;  // next chunk
        uint4 qpre0, qpre1, vpre0, vpre1;
        if (cn < NCHUNK) {
            const u16* qn = qsrc + (size_t)cn * 32 * D_;
            const u16* vn = vsrc + cn * 32;
            qpre0 = *(const uint4*)qn;
            qpre1 = *(const uint4*)(qn + (size_t)16 * D_);
            vpre0 = *(const uint4*)vn;
            vpre1 = *(const uint4*)(vn + (size_t)64 * N_);
        }
        // wave-uniform irs slice (scalar loads, off the DS pipe)
        const float* irp = irsb + nb;
        float si[32];
#pragma unroll
        for (int j = 0; j < 32; ++j) si[j] = irp[j];

        // E tile: rows n = nb + [0,32), cols m ; two independent MFMA chains
        f32x16 ea, eb;
#pragma unroll
        for (int i = 0; i < 16; ++i) { ea[i] = 0.f; eb[i] = 0.f; }
        __builtin_amdgcn_s_setprio(1);
#pragma unroll
        for (int dblk = 0; dblk < 4; ++dblk) {
            bf16x8 aq0 = *(const bf16x8*)(qs[cur] + l31 * QS_STRIDE + (2 * dblk + hi) * 8);
            bf16x8 aq1 = *(const bf16x8*)(qs[cur] + l31 * QS_STRIDE + (2 * (dblk + 4) + hi) * 8);
            ea = __builtin_amdgcn_mfma_f32_32x32x16_bf16(aq0, bq[dblk], ea, 0, 0, 0);
            eb = __builtin_amdgcn_mfma_f32_32x32x16_bf16(aq1, bq[dblk + 4], eb, 0, 0, 0);
        }
        __builtin_amdgcn_s_setprio(0);
        // S = exp2(E-64)*irs[n]; pack (cvt_pk); transpose via shfl_xor + select
        uint4 bpA0, bpA1;
        {
            u32 A[8];
#pragma unroll
            for (int i = 0; i < 8; ++i) {
                const int cc = 2 * (i & 1) + 8 * (i >> 1);  // == (2i&3)+8*((2i)>>2)
                float ir0 = hi ? si[cc + 4] : si[cc];
                float ir1 = hi ? si[cc + 5] : si[cc + 1];
                float p0 = EXP2(ea[2 * i] + eb[2 * i] - 64.0f) * ir0;
                float p1 = EXP2(ea[2 * i + 1] + eb[2 * i + 1] - 64.0f) * ir1;
                cs += p0 + p1;
                A[i] = cvtpk(p0, p1);
            }
            u32 X0 = (u32)__shfl_xor((int)A[0], 32), X1 = (u32)__shfl_xor((int)A[1], 32);
            u32 X2 = (u32)__shfl_xor((int)A[2], 32), X3 = (u32)__shfl_xor((int)A[3], 32);
            u32 X4 = (u32)__shfl_xor((int)A[4], 32), X5 = (u32)__shfl_xor((int)A[5], 32);
            u32 X6 = (u32)__shfl_xor((int)A[6], 32), X7 = (u32)__shfl_xor((int)A[7], 32);
            bpA0 = (uint4){hi ? X2 : A[0], hi ? X3 : A[1], hi ? A[2] : X0, hi ? A[3] : X1};
            bpA1 = (uint4){hi ? X6 : A[4], hi ? X7 : A[5], hi ? A[6] : X4, hi ? A[7] : X5};
        }
        __builtin_amdgcn_s_setprio(1);
#pragma unroll
        for (int nblk = 0; nblk < 2; ++nblk) {
            bf16x8 bp = __builtin_bit_cast(bf16x8, nblk ? bpA1 : bpA0);
#pragma unroll
            for (int dblk = 0; dblk < 4; ++dblk) {
                bf16x8 av = *(const bf16x8*)(vs[cur] + (dblk * 32 + l31) * VS_STRIDE +
                                             (nblk * 2 + hi) * 8);
                acc[dblk] = __builtin_amdgcn_mfma_f32_32x32x16_bf16(av, bp, acc[dblk], 0, 0, 0);
            }
        }
        __builtin_amdgcn_s_setprio(0);
        if (cn < NCHUNK) {
            *(uint4*)&qs[cur ^ 1][qoff] = qpre0;
            *(uint4*)&qs[cur ^ 1][qoff + 16 * QS_STRIDE] = qpre1;
            *(uint4*)&vs[cur ^ 1][voff] = vpre0;
            *(uint4*)&vs[cur ^ 1][voff + 64 * VS_STRIDE] = vpre1;
        }
        __syncthreads();
    }
    cs += __shfl_xor(cs, 32);
    if (lane < 32) csp[((size_t)s * B_ + b) * N_ + m0 + l31] = cs;
    // epilogue: d(r=2j) = dblk*32 + 2(j&1) + 8(j>>1) + 4hi, d(2j+1) = d+1 ->
    // pack pair into u32 row (d>>1); one full 128B line per store instruction
    u32* rpb = Rp32 + ((size_t)s * B_ + b) * (size_t)(D_ / 2) * N_;
#pragma unroll
    for (int dblk = 0; dblk < 4; ++dblk) {
#pragma unroll
        for (int j = 0; j < 8; ++j) {
            const int row = dblk * 16 + (j & 1) + 4 * (j >> 1) + 2 * hi;
            u32 pk = cvtpk(acc[dblk][2 * j], acc[dblk][2 * j + 1]);
            rpb[(size_t)row * N_ + m0 + l31] = pk;
        }
    }
}

// ---------------- K5: u = x - R*ics; out = x + relu(BN(Wt u + bt)), 8 waves ----------------
__global__ __launch_bounds__(512) void k_final(
        const float* __restrict__ x, const float* __restrict__ Wt,
        const float* __restrict__ bt, const float* __restrict__ gamma,
        const float* __restrict__ beta, const float* __restrict__ rmean,
        const float* __restrict__ rvar, const u32* __restrict__ Rp32,
        const float* __restrict__ csp, float* __restrict__ out) {
    __shared__ float us[128 * 65];
    __shared__ float icss[64];
    const int bid = blockIdx.x;
    const int b = bid >> 6;
    const int n0 = (bid & 63) << 6;
    const int t = threadIdx.x, lane = t & 63, w = t >> 6;
    const int l15 = lane & 15, g = lane >> 4;
    if (t < 64) {
        float s = 0.f;
#pragma unroll
        for (int sp = 0; sp < NS2; ++sp)
            s += csp[((size_t)sp * B_ + b) * N_ + n0 + t];
        icss[t] = 1.0f / (1e-9f + s);
    }
    __syncthreads();
    const float* xb = x + (size_t)b * C_ * N_;
    for (int i = 0; i < 8; ++i) {
        int idx = i * 512 + t;
        int dp = idx >> 6, n = idx & 63;
        float r0 = 0.f, r1 = 0.f;
#pragma unroll
        for (int sp = 0; sp < NS2; ++sp) {
            u32 v = Rp32[(((size_t)(sp * B_ + b) * (D_ / 2)) + dp) * N_ + n0 + n];
            r0 += bf2f((u16)(v & 0xffffu));
            r1 += bf2f((u16)(v >> 16));
        }
        float ic = icss[n];
        us[(2 * dp) * 65 + n]     = xb[(size_t)(2 * dp) * N_ + n0 + n]     - r0 * ic;
        us[(2 * dp + 1) * 65 + n] = xb[(size_t)(2 * dp + 1) * N_ + n0 + n] - r1 * ic;
    }
    __syncthreads();
    const int cg = w & 3;          // column group (16 cols)
    const int ct0 = (w >> 2) * 4;  // this wave's 4 ct slices
    bf16x8 uf[4];  // B-operand: cols n = n0+16cg+l15, k = d
#pragma unroll
    for (int kk = 0; kk < 4; ++kk) {
        float tmp[8];
#pragma unroll
        for (int j = 0; j < 8; ++j) tmp[j] = us[(kk * 32 + g * 8 + j) * 65 + (16 * cg + l15)];
        uf[kk] = pack8(tmp, 1.0f);
    }
    for (int cti = 0; cti < 4; ++cti) {
        const int ct = ct0 + cti;
        const int c = ct * 16 + l15;
        bf16x8 wf[4];
#pragma unroll
        for (int kk = 0; kk < 4; ++kk) {
            const float* p = Wt + (size_t)c * D_ + kk * 32 + g * 8;
            float a[8];
#pragma unroll
            for (int j = 0; j < 8; ++j) a[j] = p[j];
            wf[kk] = pack8(a, 1.0f);
        }
        f32x4 acc = {0.f, 0.f, 0.f, 0.f};
        __builtin_amdgcn_s_setprio(1);
#pragma unroll
        for (int kk = 0; kk < 4; ++kk)
            acc = __builtin_amdgcn_mfma_f32_16x16x32_bf16(wf[kk], uf[kk], acc, 0, 0, 0);
        __builtin_amdgcn_s_setprio(0);
#pragma unroll
        for (int r = 0; r < 4; ++r) {
            const int cc = ct * 16 + g * 4 + r;
            const int nn = n0 + 16 * cg + l15;
            float y = acc[r] + bt[cc];
            float bn = gamma[cc] * (y - rmean[cc]) * rsqrtf(rvar[cc] + 1e-5f) + beta[cc];
            float rl = fmaxf(bn, 0.0f);
            out[((size_t)b * C_ + cc) * N_ + nn] = xb[(size_t)cc * N_ + nn] + rl;
        }
    }
}

extern "C" void kernel_launch(void* const* d_in, const int* in_sizes, int n_in,
                              void* d_out, int out_size, void* d_ws, size_t ws_size,
                              hipStream_t stream) {
    (void)in_sizes; (void)n_in; (void)out_size; (void)ws_size;
    const float* x     = (const float*)d_in[0];
    const float* Wqk   = (const float*)d_in[1];
    const float* Wv    = (const float*)d_in[2];
    const float* bv    = (const float*)d_in[3];
    const float* Wt    = (const float*)d_in[4];
    const float* bt    = (const float*)d_in[5];
    const float* gamma = (const float*)d_in[6];
    const float* beta  = (const float*)d_in[7];
    const float* rmean = (const float*)d_in[8];
    const float* rvar  = (const float*)d_in[9];
    float* out = (float*)d_out;

    char* ws = (char*)d_ws;
    u16*   Qbf = (u16*)(ws);                        // 4 MB
    u16*   Vbf = (u16*)(ws + 4194304);              // 4 MB
    float* rsp = (float*)(ws + 8388608);            // 16*4*4096*4 = 1 MB
    float* irs = (float*)(ws + 9437184);            // 64 KB
    float* csp = (float*)(ws + 9502720);            // 6*4*4096*4 = 384 KB
    u32*   Rp  = (u32*)(ws + 9895936);              // 6*4*64*4096*4 = 25.17 MB (end ~35 MB)

    k_proj  <<<B_ * 64,      256, 0, stream>>>(x, Wqk, Wv, bv, Qbf, Vbf);
    k_pass1 <<<B_ * 8 * NS1, 512, 0, stream>>>(Qbf, rsp);
    k_irs   <<<(B_ * N_ + 255) / 256, 256, 0, stream>>>(rsp, irs);
    k_pass2 <<<B_ * 32 * NS2, 256, 0, stream>>>(Qbf, Vbf, irs, Rp, csp);
    k_final <<<B_ * 64,      512, 0, stream>>>(x, Wt, bt, gamma, beta, rmean, rvar, Rp, csp, out);
}

// Round 21
// 113.136 us; speedup vs baseline: 1.0766x; 1.0766x over previous
//
#include <hip/hip_runtime.h>
#include <hip/hip_bf16.h>

typedef unsigned int u32;
typedef unsigned short u16;
using bf16x8 = __attribute__((ext_vector_type(8))) short;
using f32x4  = __attribute__((ext_vector_type(4))) float;
using f32x16 = __attribute__((ext_vector_type(16))) float;

#define B_ 4
#define C_ 128
#define N_ 4096
#define D_ 128
#define NS1 8            // pass1 s-split (grid 1024 = 4 blocks/CU exact)
#define NSEG (N_ / NS1)  // 512 n per pass1 slice
#define NCH (NSEG / 32)
#define NS2 6            // pass2 s-split (grid 768)
#define NCHUNK (N_ / 32) // 128 total 32-n chunks

// padded LDS strides (u16 units): 272B and 80B rows -> even bank spread
#define QS_STRIDE 136
#define VS_STRIDE 40
#define XS_STRIDE 68     // f32 units; 272B rows, 16B-aligned for float4 stores

__device__ __forceinline__ u16 f2bf(float f) {
    u32 x = __builtin_bit_cast(u32, f);
    x = x + 0x7fffu + ((x >> 16) & 1u);
    return (u16)(x >> 16);
}
__device__ __forceinline__ float bf2f(u16 h) {
    return __builtin_bit_cast(float, (u32)h << 16);
}
// pack two f32 -> one u32 of 2x bf16 (RNE), single VALU inst
__device__ __forceinline__ u32 cvtpk(float lo, float hi) {
    u32 d;
    asm("v_cvt_pk_bf16_f32 %0, %1, %2" : "=v"(d) : "v"(lo), "v"(hi));
    return d;
}
#define EXP2 __builtin_amdgcn_exp2f
__device__ __forceinline__ bf16x8 pack8(const float* v, float s) {
    bf16x8 r;
#pragma unroll
    for (int j = 0; j < 8; ++j) r[j] = (short)f2bf(v[j] * s);
    return r;
}

// ---------------- K1: projections ----------------
// Qbf[b][n][d] = sqrt(log2e) * sum_c Wqk[d][c] x[b][c][n]   (bf16)
// Vbf[b][d][n] = sum_c Wv[d][c] x[b][c][n] + bv[d]          (bf16)
__global__ __launch_bounds__(256) void k_proj(
        const float* __restrict__ x, const float* __restrict__ Wqk,
        const float* __restrict__ Wv, const float* __restrict__ bv,
        u16* __restrict__ Qbf, u16* __restrict__ Vbf) {
    __shared__ __align__(16) float xs[C_ * XS_STRIDE];
    const int bid = blockIdx.x;
    const int b  = bid >> 6;
    const int n0 = (bid & 63) << 6;
    const int t  = threadIdx.x;
    const float* xb = x + (size_t)b * C_ * N_;
#pragma unroll
    for (int i = 0; i < 8; ++i) {   // 128 rows x 16 float4 (vectorized staging)
        int idx = i * 256 + t;
        int c = idx >> 4, n4 = (idx & 15) * 4;
        *(float4*)&xs[c * XS_STRIDE + n4] = *(const float4*)&xb[(size_t)c * N_ + n0 + n4];
    }
    __syncthreads();
    const int lane = t & 63, w = t >> 6;
    const int l15 = lane & 15, g = lane >> 4;
    const float SC = 1.2011224087864498f;  // sqrt(log2(e))

    bf16x8 xf[4];  // A-frag rows n = n0+16w+l15, k = c
#pragma unroll
    for (int kk = 0; kk < 4; ++kk) {
        float tmp[8];
#pragma unroll
        for (int j = 0; j < 8; ++j) tmp[j] = xs[(kk * 32 + g * 8 + j) * XS_STRIDE + (16 * w + l15)];
        xf[kk] = pack8(tmp, 1.0f);
    }
    for (int dt = 0; dt < 8; ++dt) {
        const int d = dt * 16 + l15;
        bf16x8 wq[4], wv[4];
#pragma unroll
        for (int kk = 0; kk < 4; ++kk) {
            const float* pq = Wqk + (size_t)d * C_ + kk * 32 + g * 8;
            const float* pv = Wv  + (size_t)d * C_ + kk * 32 + g * 8;
            float a[8], c8[8];
#pragma unroll
            for (int j = 0; j < 8; ++j) { a[j] = pq[j]; c8[j] = pv[j]; }
            wq[kk] = pack8(a, SC);
            wv[kk] = pack8(c8, 1.0f);
        }
        f32x4 aq = {0.f, 0.f, 0.f, 0.f}, av = {0.f, 0.f, 0.f, 0.f};
        __builtin_amdgcn_s_setprio(1);
#pragma unroll
        for (int kk = 0; kk < 4; ++kk) {
            aq = __builtin_amdgcn_mfma_f32_16x16x32_bf16(xf[kk], wq[kk], aq, 0, 0, 0);
            av = __builtin_amdgcn_mfma_f32_16x16x32_bf16(wv[kk], xf[kk], av, 0, 0, 0);
        }
        __builtin_amdgcn_s_setprio(0);
#pragma unroll
        for (int r = 0; r < 4; ++r) {
            int nn = n0 + 16 * w + g * 4 + r;
            Qbf[((size_t)b * N_ + nn) * D_ + dt * 16 + l15] = f2bf(aq[r]);
            int dd = dt * 16 + g * 4 + r;
            Vbf[((size_t)b * D_ + dd) * N_ + n0 + 16 * w + l15] = f2bf(av[r] + bv[dd]);
        }
    }
}

// ---------------- K2: row sums of exp2(E'-64), LDS dbuf, 1 barrier/iter ----------------
// grid: bid = ((b*32 + ntile)<<3) + s ; 4 waves, wave w owns n = ntile*128 + w*32 + [0,32)
__global__ __launch_bounds__(256, 4) void k_pass1(const u16* __restrict__ Qbf,
                                                  float* __restrict__ rsp) {
    __shared__ __align__(16) u16 qs[2][32 * QS_STRIDE];
    int bid = blockIdx.x;
    const int s = bid & 7; bid >>= 3;
    const int ntile = bid & 31; const int b = bid >> 5;
    const int t = threadIdx.x, lane = t & 63, w = t >> 6;
    const int l31 = lane & 31, hi = lane >> 5;
    const int nb = ntile * 128 + w * 32;

    // B-frags: col n = nb + l31, k d = dblk*16 + hi*8 + j  (once per block)
    bf16x8 bqn[8];
    {
        const u16* qn = Qbf + ((size_t)b * N_ + nb + l31) * D_ + hi * 8;
#pragma unroll
        for (int dblk = 0; dblk < 8; ++dblk) bqn[dblk] = *(const bf16x8*)(qn + dblk * 16);
    }
    // staging map: thread t -> rows t>>4 and 16+(t>>4), granule t&15 (coalesced)
    const int srow = t >> 4, sslot = t & 15;
    const u16* qsrc = Qbf + ((size_t)b * N_ + s * NSEG + srow) * D_ + sslot * 8;
    const int qoff = srow * QS_STRIDE + sslot * 8;

    // prologue: stage chunk 0
    {
        uint4 a0 = *(const uint4*)qsrc;
        uint4 a1 = *(const uint4*)(qsrc + (size_t)16 * D_);
        *(uint4*)&qs[0][qoff] = a0;
        *(uint4*)&qs[0][qoff + 16 * QS_STRIDE] = a1;
    }
    __syncthreads();

    float rs0 = 0.f, rs1 = 0.f;
    for (int mc = 0; mc < NCH; ++mc) {
        const int cur = mc & 1;
        uint4 qpre0, qpre1;
        if (mc < NCH - 1) {
            qpre0 = *(const uint4*)(qsrc + (size_t)(mc + 1) * 32 * D_);
            qpre1 = *(const uint4*)(qsrc + (size_t)((mc + 1) * 32 + 16) * D_);
        }
        f32x16 ea, eb;
#pragma unroll
        for (int i = 0; i < 16; ++i) { ea[i] = 0.f; eb[i] = 0.f; }
        __builtin_amdgcn_s_setprio(1);
#pragma unroll
        for (int dblk = 0; dblk < 4; ++dblk) {
            bf16x8 am0 = *(const bf16x8*)(qs[cur] + l31 * QS_STRIDE + (2 * dblk + hi) * 8);
            bf16x8 am1 = *(const bf16x8*)(qs[cur] + l31 * QS_STRIDE + (2 * (dblk + 4) + hi) * 8);
            ea = __builtin_amdgcn_mfma_f32_32x32x16_bf16(am0, bqn[dblk], ea, 0, 0, 0);
            eb = __builtin_amdgcn_mfma_f32_32x32x16_bf16(am1, bqn[dblk + 4], eb, 0, 0, 0);
        }
        __builtin_amdgcn_s_setprio(0);
#pragma unroll
        for (int r = 0; r < 16; r += 2) {
            rs0 += EXP2(ea[r] + eb[r] - 64.0f);
            rs1 += EXP2(ea[r + 1] + eb[r + 1] - 64.0f);
        }
        if (mc < NCH - 1) {
            *(uint4*)&qs[cur ^ 1][qoff] = qpre0;
            *(uint4*)&qs[cur ^ 1][qoff + 16 * QS_STRIDE] = qpre1;
        }
        __syncthreads();
    }
    float rs = rs0 + rs1;
    rs += __shfl_xor(rs, 32);
    if (lane < 32) rsp[((size_t)s * B_ + b) * N_ + nb + l31] = rs;
}

// ---------------- K3: irs = 1/sum_s(rsp) ----------------
__global__ void k_irs(const float* __restrict__ rsp, float* __restrict__ irs) {
    int i = blockIdx.x * 256 + threadIdx.x;
    if (i < B_ * N_) {
        float s = 0.f;
#pragma unroll
        for (int sp = 0; sp < NS1; ++sp) s += rsp[(size_t)sp * B_ * N_ + i];
        irs[i] = 1.0f / s;
    }
}

// ---------------- K4: R^T + cs partials; round-robin chunks ----------------
// grid: bid = (b*32 + mtile)*6 + s ; 4 waves, wave w owns m = mtile*128 + w*32 + [0,32)
// block s processes chunks c = s, s+6, s+12, ... (< 128)
__global__ __launch_bounds__(256, 3) void k_pass2(
        const u16* __restrict__ Qbf, const u16* __restrict__ Vbf,
        const float* __restrict__ irs, u32* __restrict__ Rp32,
        float* __restrict__ csp) {
    __shared__ __align__(16) u16 qs[2][32 * QS_STRIDE];
    __shared__ __align__(16) u16 vs[2][128 * VS_STRIDE];
    int bid = blockIdx.x;
    const int s = bid % NS2; bid /= NS2;
    const int mtile = bid & 31; const int b = bid >> 5;
    const int t = threadIdx.x, lane = t & 63, w = t >> 6;
    const int l31 = lane & 31, hi = lane >> 5;
    const int m0 = mtile * 128 + w * 32;

    // bq: E B-frags, col m = m0 + l31, k d  (once per block)
    bf16x8 bq[8];
    {
        const u16* qm = Qbf + ((size_t)b * N_ + m0 + l31) * D_ + hi * 8;
#pragma unroll
        for (int dblk = 0; dblk < 8; ++dblk) bq[dblk] = *(const bf16x8*)(qm + dblk * 16);
    }
    f32x16 acc[4];
#pragma unroll
    for (int i = 0; i < 4; ++i)
#pragma unroll
        for (int r = 0; r < 16; ++r) acc[i][r] = 0.f;
    float cs = 0.f;
    const float* irsb = irs + (size_t)b * N_;

    // staging maps (coalesced global -> padded LDS), 256 thr covers 2 rows each
    const int qrow = t >> 4, qslot = t & 15;          // Q: rows qrow, qrow+16
    const u16* qsrc = Qbf + ((size_t)b * N_ + qrow) * D_ + qslot * 8;
    const int qoff = qrow * QS_STRIDE + qslot * 8;
    const int vd = t >> 2, vslot = t & 3;             // V: rows vd, vd+64
    const u16* vsrc = Vbf + ((size_t)b * D_ + vd) * N_ + vslot * 8;
    const int voff = vd * VS_STRIDE + vslot * 8;

    // prologue: stage chunk c = s
    {
        const u16* q0 = qsrc + (size_t)s * 32 * D_;
        const u16* v0 = vsrc + s * 32;
        uint4 a0 = *(const uint4*)q0;
        uint4 a1 = *(const uint4*)(q0 + (size_t)16 * D_);
        uint4 b0 = *(const uint4*)v0;
        uint4 b1 = *(const uint4*)(v0 + (size_t)64 * N_);
        *(uint4*)&qs[0][qoff] = a0;
        *(uint4*)&qs[0][qoff + 16 * QS_STRIDE] = a1;
        *(uint4*)&vs[0][voff] = b0;
        *(uint4*)&vs[0][voff + 64 * VS_STRIDE] = b1;
    }
    __syncthreads();

    int iter = 0;
    for (int c = s; c < NCHUNK; c += NS2, ++iter) {
        const int cur = iter & 1;
        const int nb = c * 32;
        const int cn = c + NS2;  // next chunk
        uint4 qpre0, qpre1, vpre0, vpre1;
        if (cn < NCHUNK) {
            const u16* qn = qsrc + (size_t)cn * 32 * D_;
            const u16* vn = vsrc + cn * 32;
            qpre0 = *(const uint4*)qn;
            qpre1 = *(const uint4*)(qn + (size_t)16 * D_);
            vpre0 = *(const uint4*)vn;
            vpre1 = *(const uint4*)(vn + (size_t)64 * N_);
        }
        // wave-uniform irs slice (scalar loads, off the DS pipe)
        const float* irp = irsb + nb;
        float si[32];
#pragma unroll
        for (int j = 0; j < 32; ++j) si[j] = irp[j];

        // E tile: rows n = nb + [0,32), cols m ; two independent MFMA chains
        f32x16 ea, eb;
#pragma unroll
        for (int i = 0; i < 16; ++i) { ea[i] = 0.f; eb[i] = 0.f; }
        __builtin_amdgcn_s_setprio(1);
#pragma unroll
        for (int dblk = 0; dblk < 4; ++dblk) {
            bf16x8 aq0 = *(const bf16x8*)(qs[cur] + l31 * QS_STRIDE + (2 * dblk + hi) * 8);
            bf16x8 aq1 = *(const bf16x8*)(qs[cur] + l31 * QS_STRIDE + (2 * (dblk + 4) + hi) * 8);
            ea = __builtin_amdgcn_mfma_f32_32x32x16_bf16(aq0, bq[dblk], ea, 0, 0, 0);
            eb = __builtin_amdgcn_mfma_f32_32x32x16_bf16(aq1, bq[dblk + 4], eb, 0, 0, 0);
        }
        __builtin_amdgcn_s_setprio(0);
        // S = exp2(E-64)*irs[n]; pack (cvt_pk); transpose via shfl_xor + select
        uint4 bpA0, bpA1;
        {
            u32 A[8];
#pragma unroll
            for (int i = 0; i < 8; ++i) {
                const int cc = 2 * (i & 1) + 8 * (i >> 1);  // == (2i&3)+8*((2i)>>2)
                float ir0 = hi ? si[cc + 4] : si[cc];
                float ir1 = hi ? si[cc + 5] : si[cc + 1];
                float p0 = EXP2(ea[2 * i] + eb[2 * i] - 64.0f) * ir0;
                float p1 = EXP2(ea[2 * i + 1] + eb[2 * i + 1] - 64.0f) * ir1;
                cs += p0 + p1;
                A[i] = cvtpk(p0, p1);
            }
            u32 X0 = (u32)__shfl_xor((int)A[0], 32), X1 = (u32)__shfl_xor((int)A[1], 32);
            u32 X2 = (u32)__shfl_xor((int)A[2], 32), X3 = (u32)__shfl_xor((int)A[3], 32);
            u32 X4 = (u32)__shfl_xor((int)A[4], 32), X5 = (u32)__shfl_xor((int)A[5], 32);
            u32 X6 = (u32)__shfl_xor((int)A[6], 32), X7 = (u32)__shfl_xor((int)A[7], 32);
            bpA0 = (uint4){hi ? X2 : A[0], hi ? X3 : A[1], hi ? A[2] : X0, hi ? A[3] : X1};
            bpA1 = (uint4){hi ? X6 : A[4], hi ? X7 : A[5], hi ? A[6] : X4, hi ? A[7] : X5};
        }
        __builtin_amdgcn_s_setprio(1);
#pragma unroll
        for (int nblk = 0; nblk < 2; ++nblk) {
            bf16x8 bp = __builtin_bit_cast(bf16x8, nblk ? bpA1 : bpA0);
#pragma unroll
            for (int dblk = 0; dblk < 4; ++dblk) {
                bf16x8 av = *(const bf16x8*)(vs[cur] + (dblk * 32 + l31) * VS_STRIDE +
                                             (nblk * 2 + hi) * 8);
                acc[dblk] = __builtin_amdgcn_mfma_f32_32x32x16_bf16(av, bp, acc[dblk], 0, 0, 0);
            }
        }
        __builtin_amdgcn_s_setprio(0);
        if (cn < NCHUNK) {
            *(uint4*)&qs[cur ^ 1][qoff] = qpre0;
            *(uint4*)&qs[cur ^ 1][qoff + 16 * QS_STRIDE] = qpre1;
            *(uint4*)&vs[cur ^ 1][voff] = vpre0;
            *(uint4*)&vs[cur ^ 1][voff + 64 * VS_STRIDE] = vpre1;
        }
        __syncthreads();
    }
    cs += __shfl_xor(cs, 32);
    if (lane < 32) csp[((size_t)s * B_ + b) * N_ + m0 + l31] = cs;
    // epilogue: d(r=2j) = dblk*32 + 2(j&1) + 8(j>>1) + 4hi, d(2j+1) = d+1 ->
    // pack pair into u32 row (d>>1); one full 128B line per store instruction
    u32* rpb = Rp32 + ((size_t)s * B_ + b) * (size_t)(D_ / 2) * N_;
#pragma unroll
    for (int dblk = 0; dblk < 4; ++dblk) {
#pragma unroll
        for (int j = 0; j < 8; ++j) {
            const int row = dblk * 16 + (j & 1) + 4 * (j >> 1) + 2 * hi;
            u32 pk = cvtpk(acc[dblk][2 * j], acc[dblk][2 * j + 1]);
            rpb[(size_t)row * N_ + m0 + l31] = pk;
        }
    }
}

// ---------------- K5: u = x - R*ics; out = x + relu(BN(Wt u + bt)), 8 waves ----------------
__global__ __launch_bounds__(512) void k_final(
        const float* __restrict__ x, const float* __restrict__ Wt,
        const float* __restrict__ bt, const float* __restrict__ gamma,
        const float* __restrict__ beta, const float* __restrict__ rmean,
        const float* __restrict__ rvar, const u32* __restrict__ Rp32,
        const float* __restrict__ csp, float* __restrict__ out) {
    __shared__ float us[128 * 65];
    __shared__ float icss[64];
    const int bid = blockIdx.x;
    const int b = bid >> 6;
    const int n0 = (bid & 63) << 6;
    const int t = threadIdx.x, lane = t & 63, w = t >> 6;
    const int l15 = lane & 15, g = lane >> 4;
    if (t < 64) {
        float s = 0.f;
#pragma unroll
        for (int sp = 0; sp < NS2; ++sp)
            s += csp[((size_t)sp * B_ + b) * N_ + n0 + t];
        icss[t] = 1.0f / (1e-9f + s);
    }
    __syncthreads();
    const float* xb = x + (size_t)b * C_ * N_;
    for (int i = 0; i < 8; ++i) {
        int idx = i * 512 + t;
        int dp = idx >> 6, n = idx & 63;
        float r0 = 0.f, r1 = 0.f;
#pragma unroll
        for (int sp = 0; sp < NS2; ++sp) {
            u32 v = Rp32[(((size_t)(sp * B_ + b) * (D_ / 2)) + dp) * N_ + n0 + n];
            r0 += bf2f((u16)(v & 0xffffu));
            r1 += bf2f((u16)(v >> 16));
        }
        float ic = icss[n];
        us[(2 * dp) * 65 + n]     = xb[(size_t)(2 * dp) * N_ + n0 + n]     - r0 * ic;
        us[(2 * dp + 1) * 65 + n] = xb[(size_t)(2 * dp + 1) * N_ + n0 + n] - r1 * ic;
    }
    __syncthreads();
    const int cg = w & 3;          // column group (16 cols)
    const int ct0 = (w >> 2) * 4;  // this wave's 4 ct slices
    bf16x8 uf[4];  // B-operand: cols n = n0+16cg+l15, k = d
#pragma unroll
    for (int kk = 0; kk < 4; ++kk) {
        float tmp[8];
#pragma unroll
        for (int j = 0; j < 8; ++j) tmp[j] = us[(kk * 32 + g * 8 + j) * 65 + (16 * cg + l15)];
        uf[kk] = pack8(tmp, 1.0f);
    }
    for (int cti = 0; cti < 4; ++cti) {
        const int ct = ct0 + cti;
        const int c = ct * 16 + l15;
        bf16x8 wf[4];
#pragma unroll
        for (int kk = 0; kk < 4; ++kk) {
            const float* p = Wt + (size_t)c * D_ + kk * 32 + g * 8;
            float a[8];
#pragma unroll
            for (int j = 0; j < 8; ++j) a[j] = p[j];
            wf[kk] = pack8(a, 1.0f);
        }
        f32x4 acc = {0.f, 0.f, 0.f, 0.f};
        __builtin_amdgcn_s_setprio(1);
#pragma unroll
        for (int kk = 0; kk < 4; ++kk)
            acc = __builtin_amdgcn_mfma_f32_16x16x32_bf16(wf[kk], uf[kk], acc, 0, 0, 0);
        __builtin_amdgcn_s_setprio(0);
#pragma unroll
        for (int r = 0; r < 4; ++r) {
            const int cc = ct * 16 + g * 4 + r;
            const int nn = n0 + 16 * cg + l15;
            float y = acc[r] + bt[cc];
            float bn = gamma[cc] * (y - rmean[cc]) * rsqrtf(rvar[cc] + 1e-5f) + beta[cc];
            float rl = fmaxf(bn, 0.0f);
            out[((size_t)b * C_ + cc) * N_ + nn] = xb[(size_t)cc * N_ + nn] + rl;
        }
    }
}

extern "C" void kernel_launch(void* const* d_in, const int* in_sizes, int n_in,
                              void* d_out, int out_size, void* d_ws, size_t ws_size,
                              hipStream_t stream) {
    (void)in_sizes; (void)n_in; (void)out_size; (void)ws_size;
    const float* x     = (const float*)d_in[0];
    const float* Wqk   = (const float*)d_in[1];
    const float* Wv    = (const float*)d_in[2];
    const float* bv    = (const float*)d_in[3];
    const float* Wt    = (const float*)d_in[4];
    const float* bt    = (const float*)d_in[5];
    const float* gamma = (const float*)d_in[6];
    const float* beta  = (const float*)d_in[7];
    const float* rmean = (const float*)d_in[8];
    const float* rvar  = (const float*)d_in[9];
    float* out = (float*)d_out;

    char* ws = (char*)d_ws;
    u16*   Qbf = (u16*)(ws);                        // 4 MB
    u16*   Vbf = (u16*)(ws + 4194304);              // 4 MB
    float* rsp = (float*)(ws + 8388608);            // 8*4*4096*4 = 512 KB
    float* irs = (float*)(ws + 8912896);            // 64 KB
    float* csp = (float*)(ws + 8978432);            // 6*4*4096*4 = 384 KB
    u32*   Rp  = (u32*)(ws + 9371648);              // 6*4*64*4096*4 = 25.17 MB (end ~34.5 MB)

    k_proj  <<<B_ * 64,       256, 0, stream>>>(x, Wqk, Wv, bv, Qbf, Vbf);
    k_pass1 <<<B_ * 32 * NS1, 256, 0, stream>>>(Qbf, rsp);
    k_irs   <<<(B_ * N_ + 255) / 256, 256, 0, stream>>>(rsp, irs);
    k_pass2 <<<B_ * 32 * NS2, 256, 0, stream>>>(Qbf, Vbf, irs, Rp, csp);
    k_final <<<B_ * 64,       512, 0, stream>>>(x, Wt, bt, gamma, beta, rmean, rvar, Rp, csp, out);
}